// Round 11
// baseline (678.299 us; speedup 1.0000x reference)
//
#include <hip/hip_runtime.h>

typedef unsigned int u32;
typedef _Float16 h16;
typedef __attribute__((ext_vector_type(2))) _Float16 h2;   // 4 bytes
typedef __attribute__((ext_vector_type(4))) _Float16 h4;   // 8 bytes

// ---- workspace layout (float offsets) ----
#define WS_WSG   0        // 64x512 combined permuted  (32768 floats)
#define WS_WEG   32768    // 8x256 : Wenc @ Wgate   [m][j]  (original order)
#define WS_BALL  34816    // 256   : (benc+bsrc+bdst) @ Wgate + bgate
#define WS_GS    35328    // HG: Nx512 half | HZ: Nx256 half | ACC: Nx256 half

// packed fp16 atomic add (device-scope via sc1; no HIP overload on ROCm 7.2)
__device__ __forceinline__ void pk_add(h16* addr, float lo, float hi) {
    union { h2 h; u32 u; } cv;
    cv.h = (h2){ (h16)lo, (h16)hi };
    asm volatile("global_atomic_pk_add_f16 %0, %1, off sc1"
                 :: "v"(addr), "v"(cv.u) : "memory");
}

// ---------------------------------------------------------------- zero out
__global__ void zero_k(float* p, int n) {
    int i = blockIdx.x * blockDim.x + threadIdx.x;
    int st = gridDim.x * blockDim.x;
    for (; i < n; i += st) p[i] = 0.0f;
}

// ---------------------------------------------------------------- compose weights
// (verified round 8/10) column-permuted so HG[n][lane*4+q] = G[n][q*64+lane].
__global__ void compose_k(const float* __restrict__ Wsrc, const float* __restrict__ Wdst,
                          const float* __restrict__ Wenc, const float* __restrict__ benc,
                          const float* __restrict__ bsrc, const float* __restrict__ bdst,
                          const float* __restrict__ Wgate, const float* __restrict__ bgate,
                          float* __restrict__ ws) {
    const int j = threadIdx.x;           // 0..255 (original column)
    const int r = blockIdx.x;            // 0..72
    const int p = ((j & 63) << 2) + (j >> 6);   // permuted position
    if (r < 64) {
        float a = 0.f, b = 0.f;
        for (int c = 0; c < 64; ++c) {
            const float wg = Wgate[c * 256 + j];
            a += Wsrc[r * 64 + c] * wg;
            b += Wdst[r * 64 + c] * wg;
        }
        ws[WS_WSG + r * 512 + p] = a;
        ws[WS_WSG + r * 512 + 256 + p] = b;
    } else if (r < 72) {
        const int m = r - 64;
        float a = 0.f;
        for (int c = 0; c < 64; ++c) a += Wenc[m * 64 + c] * Wgate[c * 256 + j];
        ws[WS_WEG + m * 256 + j] = a;
    } else {
        float a = bgate[j];
        for (int c = 0; c < 64; ++c)
            a += (benc[c] + bsrc[c] + bdst[c]) * Wgate[c * 256 + j];
        ws[WS_BALL + j] = a;
    }
}

// ---------------------------------------------------------------- node precompute (fp16 out)
// (verified rounds 5/8/10)
__global__ __launch_bounds__(512, 1) void nodepre3_k(
    const float* __restrict__ emb, const float* __restrict__ Wc,
    h16* __restrict__ HG, int N) {
    __shared__ __align__(16) float sW[32768];    // 128 KB [k][512]
    __shared__ __align__(16) float sEm[1024];    // 16 node rows
    for (int i = threadIdx.x * 4; i < 32768; i += 2048)
        *(float4*)&sW[i] = *(const float4*)&Wc[i];

    const int c4 = (threadIdx.x & 127) << 2;
    const int g = threadIdx.x >> 7;
    const int lim = N * 64;
    const int ntiles = (N + 15) >> 4;

    for (int tile = blockIdx.x; tile < ntiles; tile += gridDim.x) {
        const int n0 = tile << 4;
        const int base = n0 * 64;
        __syncthreads();
        for (int i = threadIdx.x * 4; i < 1024; i += 2048) {
            const int gi = base + i;
            *(float4*)&sEm[i] = (gi < lim) ? *(const float4*)&emb[gi]
                                           : make_float4(0.f, 0.f, 0.f, 0.f);
        }
        __syncthreads();

        float4 a0 = {0,0,0,0}, a1 = {0,0,0,0}, a2 = {0,0,0,0}, a3 = {0,0,0,0};
        const float* e0p = &sEm[(g * 4 + 0) * 64];
        const float* e1p = &sEm[(g * 4 + 1) * 64];
        const float* e2p = &sEm[(g * 4 + 2) * 64];
        const float* e3p = &sEm[(g * 4 + 3) * 64];
        #pragma unroll 8
        for (int k = 0; k < 64; ++k) {
            const float4 w = *(const float4*)&sW[k * 512 + c4];
            const float e0 = e0p[k], e1 = e1p[k], e2 = e2p[k], e3 = e3p[k];
            a0.x += e0 * w.x; a0.y += e0 * w.y; a0.z += e0 * w.z; a0.w += e0 * w.w;
            a1.x += e1 * w.x; a1.y += e1 * w.y; a1.z += e1 * w.z; a1.w += e1 * w.w;
            a2.x += e2 * w.x; a2.y += e2 * w.y; a2.z += e2 * w.z; a2.w += e2 * w.w;
            a3.x += e3 * w.x; a3.y += e3 * w.y; a3.z += e3 * w.z; a3.w += e3 * w.w;
        }
        const int nb = n0 + g * 4;
        const h4 h0 = { (h16)a0.x, (h16)a0.y, (h16)a0.z, (h16)a0.w };
        const h4 h1 = { (h16)a1.x, (h16)a1.y, (h16)a1.z, (h16)a1.w };
        const h4 h2v = { (h16)a2.x, (h16)a2.y, (h16)a2.z, (h16)a2.w };
        const h4 h3 = { (h16)a3.x, (h16)a3.y, (h16)a3.z, (h16)a3.w };
        if (nb + 0 < N) *(h4*)&HG[(size_t)(nb + 0) * 512 + c4] = h0;
        if (nb + 1 < N) *(h4*)&HG[(size_t)(nb + 1) * 512 + c4] = h1;
        if (nb + 2 < N) *(h4*)&HG[(size_t)(nb + 2) * 512 + c4] = h2v;
        if (nb + 3 < N) *(h4*)&HG[(size_t)(nb + 3) * 512 + c4] = h3;
    }
}

// ---------------------------------------------------------------- z pack (fp16)
__global__ void hz_k(const float* __restrict__ z0g, const float* __restrict__ z1g,
                     h16* __restrict__ HZ, int N) {
    const int tot = N * 64;
    for (int idx = blockIdx.x * blockDim.x + threadIdx.x; idx < tot;
         idx += gridDim.x * blockDim.x) {
        const int n = idx >> 6, l = idx & 63;
        const h4 v = { (h16)z1g[n * 192 + l], (h16)z1g[n * 192 + 64 + l],
                       (h16)z1g[n * 192 + 128 + l], (h16)z0g[n * 64 + l] };
        *(h4*)&HZ[(size_t)n * 256 + (l << 2)] = v;
    }
}

// ---------------------------------------------------------------- edge kernel (ILP-2 + fp16 + pk)
// Pair (e, e+nw), outer stride 2*nw: both edges' gathers in flight per wave.
// fp16 footprint makes the 16K-edge window ~32 MB -> fits aggregate L2
// (round 7's fp32 failure was 48 MB). Messages ok-predicated, pk atomics.
struct EH {
    int s;
    float ok;
    float r0, r1, r2;
    h4 gs, gd, zv;
};

__device__ __forceinline__ EH load_edge16(
    int e, int lane, int i64s, int i64d, int N,
    const int* __restrict__ src, const int* __restrict__ dst,
    const float* __restrict__ r_ij, const h16* __restrict__ HG,
    const h16* __restrict__ HZ) {
    EH x;
    int s = i64s ? src[2 * e] : src[e];
    int t = i64d ? dst[2 * e] : dst[e];
    x.ok = 1.f;
    if (s < 0 || s >= N) { s = 0; x.ok = 0.f; }
    if (t < 0 || t >= N) { t = 0; x.ok = 0.f; }
    x.s = s;
    x.r0 = r_ij[e * 3 + 0];
    x.r1 = r_ij[e * 3 + 1];
    x.r2 = r_ij[e * 3 + 2];
    x.gs = *(const h4*)&HG[(size_t)s * 512 + (lane << 2)];
    x.gd = *(const h4*)&HG[(size_t)t * 512 + 256 + (lane << 2)];
    x.zv = *(const h4*)&HZ[(size_t)t * 256 + (lane << 2)];
    return x;
}

__device__ __forceinline__ void consume_edge16(
    const EH& x, int lane, const float* __restrict__ sWe,
    float bl0, float bl1, float bl2, float bl3, h16* __restrict__ ACC) {
    float g0 = (float)x.gs.x + (float)x.gd.x + bl0;
    float g1 = (float)x.gs.y + (float)x.gd.y + bl1;
    float g2 = (float)x.gs.z + (float)x.gd.z + bl2;
    float g3 = (float)x.gs.w + (float)x.gd.w + bl3;
    const float za = (float)x.zv.x, zb = (float)x.zv.y, zc = (float)x.zv.z;
    const float z0v = (float)x.zv.w;

    const float d = sqrtf(x.r0 * x.r0 + x.r1 * x.r1 + x.r2 * x.r2);
    #pragma unroll
    for (int m = 0; m < 8; ++m) {
        const float mu = 0.28571428571f * (float)m;   // linspace(0, 2, 8)
        const float tt = (d - mu) * 4.0f;             // / sigma, sigma = 0.25
        const float rm = __expf(-tt * tt);
        const float* wq = &sWe[(m << 8) + lane];
        g0 += rm * wq[0];
        g1 += rm * wq[64];
        g2 += rm * wq[128];
        g3 += rm * wq[192];
    }

    const float v0 = x.r0 * 3.5f, v1 = x.r1 * 3.5f, v2 = x.r2 * 3.5f;
    const float inv = rsqrtf(1.0f + v0 * v0 + v1 * v1 + v2 * v2);
    const float h0 = v0 * inv, h1 = v1 * inv, h2 = v2 * inv;
    const float uu = h0 * za + h1 * zb + h2 * zc;

    const float smsg = (g0 * z0v + g1 * uu) * x.ok;
    const float vm0 = (g2 * za + g3 * h0 * z0v) * x.ok;
    const float vm1 = (g2 * zb + g3 * h1 * z0v) * x.ok;
    const float vm2 = (g2 * zc + g3 * h2 * z0v) * x.ok;

    h16* ap = &ACC[(size_t)x.s * 256 + (lane << 2)];
    pk_add(ap,     smsg, vm0);
    pk_add(ap + 2, vm1,  vm2);
}

__global__ __launch_bounds__(256, 8) void edge_pk2_k(
    const int* __restrict__ src, const int* __restrict__ dst,
    const float* __restrict__ r_ij, const h16* __restrict__ HG,
    const h16* __restrict__ HZ, const float* __restrict__ WeG,
    const float* __restrict__ ball, h16* __restrict__ ACC, int N, int E) {
    __shared__ float sWe[2048];   // 8 KB
    __shared__ float sBall[256];  // 1 KB
    __shared__ int sFl[2];

    if (threadIdx.x == 0) {
        const u32* ps = (const u32*)src;
        const u32* pd = (const u32*)dst;
        int s64 = 1, d64 = 1;
        for (int i = 1; i < 128; i += 2) {
            if (ps[i] != 0u) s64 = 0;
            if (pd[i] != 0u) d64 = 0;
        }
        sFl[0] = s64;
        sFl[1] = d64;
    }
    for (int i = threadIdx.x; i < 2048; i += 256) sWe[i] = WeG[i];
    sBall[threadIdx.x] = ball[threadIdx.x];
    __syncthreads();

    const int wid = threadIdx.x >> 6, lane = threadIdx.x & 63;
    const int i64s = sFl[0], i64d = sFl[1];
    const int nw = gridDim.x * 4;

    const float bl0 = sBall[lane], bl1 = sBall[64 + lane];
    const float bl2 = sBall[128 + lane], bl3 = sBall[192 + lane];

    for (int e = blockIdx.x * 4 + wid; e < E; e += 2 * nw) {
        const int e2 = e + nw;
        EH A = load_edge16(e, lane, i64s, i64d, N, src, dst, r_ij, HG, HZ);
        if (e2 < E) {   // wave-uniform
            EH B = load_edge16(e2, lane, i64s, i64d, N, src, dst, r_ij, HG, HZ);
            consume_edge16(A, lane, sWe, bl0, bl1, bl2, bl3, ACC);
            consume_edge16(B, lane, sWe, bl0, bl1, bl2, bl3, ACC);
        } else {
            consume_edge16(A, lane, sWe, bl0, bl1, bl2, bl3, ACC);
        }
    }
}

// ---------------------------------------------------------------- node epilogue v4
// (verified round 10) de-interleave fp16 ACC, apply Ws/Wv, write out fully.
__global__ __launch_bounds__(256, 3) void nodepost4_k(
    const h16* __restrict__ ACC, float* __restrict__ out,
    const float* __restrict__ Ws, const float* __restrict__ Wv, int N) {
    __shared__ __align__(16) float sW[8192];     // [0..4095]=Ws, [4096..]=Wv
    __shared__ float sR[64 * 65];                // 64 virtual rows, pad 65
    for (int i = threadIdx.x * 4; i < 8192; i += 1024) {
        *(float4*)&sW[i] = (i < 4096) ? *(const float4*)&Ws[i]
                                      : *(const float4*)&Wv[i - 4096];
    }
    const int c4 = (threadIdx.x & 15) << 2;      // col offset 0..60
    const int rq = threadIdx.x >> 4;             // 0..15 -> rows rq*4..+3
    const int lim = N * 256;
    const int ntiles = (N + 15) >> 4;

    for (int tile = blockIdx.x; tile < ntiles; tile += gridDim.x) {
        const int n0 = tile << 4;
        const int base = n0 * 256;
        __syncthreads();
        for (int i = threadIdx.x * 4; i < 4096; i += 1024) {
            const int nl = i >> 8;               // node local 0..15
            const int k = (i & 255) >> 2;        // column 0..63
            h4 v = { (h16)0.f, (h16)0.f, (h16)0.f, (h16)0.f };
            if (base + i < lim) v = *(const h4*)&ACC[base + i];
            sR[(nl) * 65 + k] = (float)v.x;
            sR[(16 + nl) * 65 + k] = (float)v.y;
            sR[(32 + nl) * 65 + k] = (float)v.z;
            sR[(48 + nl) * 65 + k] = (float)v.w;
        }
        __syncthreads();

        const int rb = rq << 2;
        const int part = rb >> 4;
        const float* wb = &sW[(part == 0 ? 0 : 4096) + c4];
        float4 a0 = {0,0,0,0}, a1 = {0,0,0,0}, a2 = {0,0,0,0}, a3 = {0,0,0,0};
        const float* rp0 = &sR[(rb + 0) * 65];
        const float* rp1 = &sR[(rb + 1) * 65];
        const float* rp2 = &sR[(rb + 2) * 65];
        const float* rp3 = &sR[(rb + 3) * 65];
        #pragma unroll 8
        for (int k = 0; k < 64; ++k) {
            const float4 w = *(const float4*)&wb[k * 64];
            const float e0 = rp0[k], e1 = rp1[k], e2 = rp2[k], e3 = rp3[k];
            a0.x += e0 * w.x; a0.y += e0 * w.y; a0.z += e0 * w.z; a0.w += e0 * w.w;
            a1.x += e1 * w.x; a1.y += e1 * w.y; a1.z += e1 * w.z; a1.w += e1 * w.w;
            a2.x += e2 * w.x; a2.y += e2 * w.y; a2.z += e2 * w.z; a2.w += e2 * w.w;
            a3.x += e3 * w.x; a3.y += e3 * w.y; a3.z += e3 * w.z; a3.w += e3 * w.w;
        }
        #pragma unroll
        for (int i = 0; i < 4; ++i) {
            const int n = n0 + ((rb + i) & 15);
            if (n >= N) continue;
            const float4 av = (i == 0) ? a0 : (i == 1) ? a1 : (i == 2) ? a2 : a3;
            if (part == 0)
                *(float4*)&out[(size_t)n * 64 + c4] = av;
            else
                *(float4*)&out[(size_t)N * 64 + (size_t)n * 192 + (part - 1) * 64 + c4] = av;
        }
    }
}

// ---------------------------------------------------------------- full fallback
__global__ __launch_bounds__(512, 1) void edge_k(
    const int* __restrict__ src, const int* __restrict__ dst,
    const float* __restrict__ r_ij, const float* __restrict__ z0g,
    const float* __restrict__ z1g, const float* __restrict__ emb,
    const float* __restrict__ Wenc, const float* __restrict__ benc,
    const float* __restrict__ Wsrc, const float* __restrict__ bsrc,
    const float* __restrict__ Wdst, const float* __restrict__ bdst,
    const float* __restrict__ Wgate, const float* __restrict__ bgate,
    const float* __restrict__ Ws, const float* __restrict__ Wv,
    float* __restrict__ out, int N, int E)
{
    __shared__ float sWsrc[4096];
    __shared__ float sWdst[4096];
    __shared__ float sWg[16384];
    __shared__ float sWs[4096];
    __shared__ float sWv[4096];
    __shared__ float sWe[512];
    __shared__ float sB[64];
    __shared__ float sBg[256];
    __shared__ int sFl[2];

    if (threadIdx.x == 0) {
        const u32* ps = (const u32*)src;
        const u32* pd = (const u32*)dst;
        int s64 = 1, d64 = 1;
        for (int i = 1; i < 128; i += 2) {
            if (ps[i] != 0u) s64 = 0;
            if (pd[i] != 0u) d64 = 0;
        }
        sFl[0] = s64;
        sFl[1] = d64;
    }
    for (int i = threadIdx.x; i < 4096; i += 512) {
        sWsrc[i] = Wsrc[i];
        sWdst[i] = Wdst[i];
        sWs[i] = Ws[i];
        sWv[i] = Wv[i];
    }
    for (int i = threadIdx.x; i < 16384; i += 512) sWg[i] = Wgate[i];
    for (int i = threadIdx.x; i < 512; i += 512) sWe[i] = Wenc[i];
    if (threadIdx.x < 64)
        sB[threadIdx.x] = benc[threadIdx.x] + bsrc[threadIdx.x] + bdst[threadIdx.x];
    if (threadIdx.x < 256) sBg[threadIdx.x] = bgate[threadIdx.x];
    __syncthreads();

    const int wid = threadIdx.x >> 6, lane = threadIdx.x & 63;
    const int i64s = sFl[0], i64d = sFl[1];

    for (int e = blockIdx.x * 8 + wid; e < E; e += gridDim.x * 8) {
        const int s = i64s ? src[2 * e] : src[e];
        const int t = i64d ? dst[2 * e] : dst[e];
        if (s < 0 || s >= N || t < 0 || t >= N) continue;

        const float es = emb[s * 64 + lane];
        const float et = emb[t * 64 + lane];
        float de = sB[lane];
        #pragma unroll 8
        for (int k = 0; k < 64; ++k) {
            de += __shfl(es, k, 64) * sWsrc[(k << 6) + lane];
            de += __shfl(et, k, 64) * sWdst[(k << 6) + lane];
        }
        const float r0 = r_ij[e * 3 + 0];
        const float r1 = r_ij[e * 3 + 1];
        const float r2 = r_ij[e * 3 + 2];
        const float d = sqrtf(r0 * r0 + r1 * r1 + r2 * r2);
        #pragma unroll
        for (int m = 0; m < 8; ++m) {
            const float mu = (2.0f / 7.0f) * (float)m;
            const float tt = (d - mu) * 4.0f;
            de += __expf(-tt * tt) * sWe[m * 64 + lane];
        }

        const float v0 = r0 * 3.5f, v1 = r1 * 3.5f, v2 = r2 * 3.5f;
        const float inv = rsqrtf(1.0f + v0 * v0 + v1 * v1 + v2 * v2);
        const float h0 = v0 * inv, h1 = v1 * inv, h2 = v2 * inv;

        const float z0v = z0g[t * 64 + lane];
        const float za = z1g[t * 192 + lane];
        const float zb = z1g[t * 192 + 64 + lane];
        const float zc = z1g[t * 192 + 128 + lane];
        const float uu = h0 * za + h1 * zb + h2 * zc;

        float g0 = sBg[lane], g1 = sBg[64 + lane], g2 = sBg[128 + lane], g3 = sBg[192 + lane];
        #pragma unroll 8
        for (int k = 0; k < 64; ++k) {
            const float dk = __shfl(de, k, 64);
            const float* w = &sWg[(k << 8) + lane];
            g0 += dk * w[0];
            g1 += dk * w[64];
            g2 += dk * w[128];
            g3 += dk * w[192];
        }

        const float smsg = g0 * z0v + g1 * uu;
        const float vm0 = g2 * za + g3 * h0 * z0v;
        const float vm1 = g2 * zb + g3 * h1 * z0v;
        const float vm2 = g2 * zc + g3 * h2 * z0v;

        float p0 = 0.f, q0 = 0.f, q1 = 0.f, q2 = 0.f;
        #pragma unroll 8
        for (int k = 0; k < 64; ++k) {
            const float sk = __shfl(smsg, k, 64);
            const float a = __shfl(vm0, k, 64);
            const float b = __shfl(vm1, k, 64);
            const float c = __shfl(vm2, k, 64);
            p0 += sk * sWs[(k << 6) + lane];
            const float wv = sWv[(k << 6) + lane];
            q0 += a * wv;
            q1 += b * wv;
            q2 += c * wv;
        }

        atomicAdd(&out[s * 64 + lane], p0);
        const int b1 = N * 64 + s * 192 + lane;
        atomicAdd(&out[b1], q0);
        atomicAdd(&out[b1 + 64], q1);
        atomicAdd(&out[b1 + 128], q2);
    }
}

extern "C" void kernel_launch(void* const* d_in, const int* in_sizes, int n_in,
                              void* d_out, int out_size, void* d_ws, size_t ws_size,
                              hipStream_t stream) {
    const int* src = (const int*)d_in[0];
    const int* dst = (const int*)d_in[1];
    const float* r_ij = (const float*)d_in[2];
    const float* z0g  = (const float*)d_in[3];
    const float* z1g  = (const float*)d_in[4];
    const float* emb  = (const float*)d_in[5];
    const float* Wenc = (const float*)d_in[6];
    const float* benc = (const float*)d_in[7];
    const float* Wsrc = (const float*)d_in[8];
    const float* bsrc = (const float*)d_in[9];
    const float* Wdst = (const float*)d_in[10];
    const float* bdst = (const float*)d_in[11];
    const float* Wgate = (const float*)d_in[12];
    const float* bgate = (const float*)d_in[13];
    const float* Ws = (const float*)d_in[14];
    const float* Wv = (const float*)d_in[15];

    const int N = out_size / 256;                    // out0 N*64 + out1 N*192
    int E = in_sizes[0];
    if (in_sizes[2] / 3 < E) E = in_sizes[2] / 3;    // robustness

    float* ws = (float*)d_ws;
    const size_t need = ((size_t)WS_GS + (size_t)N * 512u + 16u) * sizeof(float);

    if (ws != nullptr && ws_size >= need) {
        compose_k<<<73, 256, 0, stream>>>(Wsrc, Wdst, Wenc, benc, bsrc, bdst,
                                          Wgate, bgate, ws);
        h16* HG = (h16*)(ws + WS_GS);
        h16* HZ = HG + (size_t)N * 512;
        h16* ACC = HZ + (size_t)N * 256;
        zero_k<<<1024, 256, 0, stream>>>((float*)ACC, N * 128);
        nodepre3_k<<<256, 512, 0, stream>>>(emb, ws + WS_WSG, HG, N);
        hz_k<<<1024, 256, 0, stream>>>(z0g, z1g, HZ, N);
        edge_pk2_k<<<2048, 256, 0, stream>>>(src, dst, r_ij, HG, HZ,
                                             ws + WS_WEG, ws + WS_BALL,
                                             ACC, N, E);
        nodepost4_k<<<2048, 256, 0, stream>>>(ACC, (float*)d_out, Ws, Wv, N);
    } else {
        zero_k<<<2048, 256, 0, stream>>>((float*)d_out, out_size);
        edge_k<<<2048, 512, 0, stream>>>(src, dst, r_ij, z0g, z1g, emb, Wenc, benc,
                                         Wsrc, bsrc, Wdst, bdst, Wgate, bgate, Ws, Wv,
                                         (float*)d_out, N, E);
    }
}

// Round 12
// 676.368 us; speedup vs baseline: 1.0029x; 1.0029x over previous
//
#include <hip/hip_runtime.h>

typedef unsigned int u32;
typedef _Float16 h16;
typedef __attribute__((ext_vector_type(2))) _Float16 h2;   // 4 bytes
typedef __attribute__((ext_vector_type(4))) _Float16 h4;   // 8 bytes

// ---- workspace layout (float offsets) ----
#define WS_WSG   0        // 64x512 combined permuted  (32768 floats)
#define WS_WEG   32768    // 8x256 : Wenc @ Wgate   [m][j]  (original order)
#define WS_BALL  34816    // 256   : (benc+bsrc+bdst) @ Wgate + bgate
#define WS_GS    35328    // HG: Nx512 half | HZ: Nx256 half | ACC: Nx256 half | RT: 4096x256 half

#define RT_BINS  4096

// packed fp16 atomic add (device-scope via sc1; no HIP overload on ROCm 7.2)
__device__ __forceinline__ void pk_add(h16* addr, float lo, float hi) {
    union { h2 h; u32 u; } cv;
    cv.h = (h2){ (h16)lo, (h16)hi };
    asm volatile("global_atomic_pk_add_f16 %0, %1, off sc1"
                 :: "v"(addr), "v"(cv.u) : "memory");
}

// ---------------------------------------------------------------- zero out
__global__ void zero_k(float* p, int n) {
    int i = blockIdx.x * blockDim.x + threadIdx.x;
    int st = gridDim.x * blockDim.x;
    for (; i < n; i += st) p[i] = 0.0f;
}

// ---------------------------------------------------------------- compose weights
// (verified round 8/10) column-permuted so HG[n][lane*4+q] = G[n][q*64+lane].
__global__ void compose_k(const float* __restrict__ Wsrc, const float* __restrict__ Wdst,
                          const float* __restrict__ Wenc, const float* __restrict__ benc,
                          const float* __restrict__ bsrc, const float* __restrict__ bdst,
                          const float* __restrict__ Wgate, const float* __restrict__ bgate,
                          float* __restrict__ ws) {
    const int j = threadIdx.x;           // 0..255 (original column)
    const int r = blockIdx.x;            // 0..72
    const int p = ((j & 63) << 2) + (j >> 6);   // permuted position
    if (r < 64) {
        float a = 0.f, b = 0.f;
        for (int c = 0; c < 64; ++c) {
            const float wg = Wgate[c * 256 + j];
            a += Wsrc[r * 64 + c] * wg;
            b += Wdst[r * 64 + c] * wg;
        }
        ws[WS_WSG + r * 512 + p] = a;
        ws[WS_WSG + r * 512 + 256 + p] = b;
    } else if (r < 72) {
        const int m = r - 64;
        float a = 0.f;
        for (int c = 0; c < 64; ++c) a += Wenc[m * 64 + c] * Wgate[c * 256 + j];
        ws[WS_WEG + m * 256 + j] = a;
    } else {
        float a = bgate[j];
        for (int c = 0; c < 64; ++c)
            a += (benc[c] + bsrc[c] + bdst[c]) * Wgate[c * 256 + j];
        ws[WS_BALL + j] = a;
    }
}

// ---------------------------------------------------------------- radial table
// RT[bin][perm(j)] = ball[j] + sum_m exp(-((d_bin-mu_m)*4)^2) * WeG[m][j]
// d_bin = bin-center over [0,4). 4096 bins -> rm error <= ~2e-3 (<< fp16 noise).
// Lane-permuted like HG so the edge kernel reads one h4 per lane.
__global__ void radtab_k(const float* __restrict__ weg, const float* __restrict__ ball,
                         h16* __restrict__ RT) {
    const int bin = blockIdx.x;          // 0..4095
    const int j = threadIdx.x;           // original col 0..255
    const float d = ((float)bin + 0.5f) * (4.0f / (float)RT_BINS);
    float a = ball[j];
    #pragma unroll
    for (int m = 0; m < 8; ++m) {
        const float mu = 0.28571428571f * (float)m;   // linspace(0, 2, 8)
        const float tt = (d - mu) * 4.0f;             // / sigma, sigma = 0.25
        a += __expf(-tt * tt) * weg[m * 256 + j];
    }
    const int p = ((j & 63) << 2) + (j >> 6);
    RT[bin * 256 + p] = (h16)a;
}

// ---------------------------------------------------------------- node precompute (fp16 out)
// (verified rounds 5/8/10)
__global__ __launch_bounds__(512, 1) void nodepre3_k(
    const float* __restrict__ emb, const float* __restrict__ Wc,
    h16* __restrict__ HG, int N) {
    __shared__ __align__(16) float sW[32768];    // 128 KB [k][512]
    __shared__ __align__(16) float sEm[1024];    // 16 node rows
    for (int i = threadIdx.x * 4; i < 32768; i += 2048)
        *(float4*)&sW[i] = *(const float4*)&Wc[i];

    const int c4 = (threadIdx.x & 127) << 2;
    const int g = threadIdx.x >> 7;
    const int lim = N * 64;
    const int ntiles = (N + 15) >> 4;

    for (int tile = blockIdx.x; tile < ntiles; tile += gridDim.x) {
        const int n0 = tile << 4;
        const int base = n0 * 64;
        __syncthreads();
        for (int i = threadIdx.x * 4; i < 1024; i += 2048) {
            const int gi = base + i;
            *(float4*)&sEm[i] = (gi < lim) ? *(const float4*)&emb[gi]
                                           : make_float4(0.f, 0.f, 0.f, 0.f);
        }
        __syncthreads();

        float4 a0 = {0,0,0,0}, a1 = {0,0,0,0}, a2 = {0,0,0,0}, a3 = {0,0,0,0};
        const float* e0p = &sEm[(g * 4 + 0) * 64];
        const float* e1p = &sEm[(g * 4 + 1) * 64];
        const float* e2p = &sEm[(g * 4 + 2) * 64];
        const float* e3p = &sEm[(g * 4 + 3) * 64];
        #pragma unroll 8
        for (int k = 0; k < 64; ++k) {
            const float4 w = *(const float4*)&sW[k * 512 + c4];
            const float e0 = e0p[k], e1 = e1p[k], e2 = e2p[k], e3 = e3p[k];
            a0.x += e0 * w.x; a0.y += e0 * w.y; a0.z += e0 * w.z; a0.w += e0 * w.w;
            a1.x += e1 * w.x; a1.y += e1 * w.y; a1.z += e1 * w.z; a1.w += e1 * w.w;
            a2.x += e2 * w.x; a2.y += e2 * w.y; a2.z += e2 * w.z; a2.w += e2 * w.w;
            a3.x += e3 * w.x; a3.y += e3 * w.y; a3.z += e3 * w.z; a3.w += e3 * w.w;
        }
        const int nb = n0 + g * 4;
        const h4 h0 = { (h16)a0.x, (h16)a0.y, (h16)a0.z, (h16)a0.w };
        const h4 h1 = { (h16)a1.x, (h16)a1.y, (h16)a1.z, (h16)a1.w };
        const h4 h2v = { (h16)a2.x, (h16)a2.y, (h16)a2.z, (h16)a2.w };
        const h4 h3 = { (h16)a3.x, (h16)a3.y, (h16)a3.z, (h16)a3.w };
        if (nb + 0 < N) *(h4*)&HG[(size_t)(nb + 0) * 512 + c4] = h0;
        if (nb + 1 < N) *(h4*)&HG[(size_t)(nb + 1) * 512 + c4] = h1;
        if (nb + 2 < N) *(h4*)&HG[(size_t)(nb + 2) * 512 + c4] = h2v;
        if (nb + 3 < N) *(h4*)&HG[(size_t)(nb + 3) * 512 + c4] = h3;
    }
}

// ---------------------------------------------------------------- z pack (fp16) + ACC zero
__global__ void hz_k(const float* __restrict__ z0g, const float* __restrict__ z1g,
                     h16* __restrict__ HZ, h16* __restrict__ ACC, int N) {
    const int tot = N * 64;
    const h4 zz = { (h16)0.f, (h16)0.f, (h16)0.f, (h16)0.f };
    for (int idx = blockIdx.x * blockDim.x + threadIdx.x; idx < tot;
         idx += gridDim.x * blockDim.x) {
        const int n = idx >> 6, l = idx & 63;
        const h4 v = { (h16)z1g[n * 192 + l], (h16)z1g[n * 192 + 64 + l],
                       (h16)z1g[n * 192 + 128 + l], (h16)z0g[n * 64 + l] };
        *(h4*)&HZ[(size_t)n * 256 + (l << 2)] = v;
        *(h4*)&ACC[(size_t)n * 256 + (l << 2)] = zz;   // fold zeroing (saves a dispatch)
    }
}

// ---------------------------------------------------------------- edge kernel (table + ILP-2 + pk)
// No LDS, no m-loop: radial gate comes from the quantized RT table (one 8B
// gather, wave-uniform row -> L2-hot). ILP-2 strided pairs; pk16 atomics.
struct EH {
    int s;
    float ok;
    float r0, r1, r2;
    h4 gs, gd, zv, rt;
};

__device__ __forceinline__ EH load_edge16(
    int e, int lane, int i64s, int i64d, int N,
    const int* __restrict__ src, const int* __restrict__ dst,
    const float* __restrict__ r_ij, const h16* __restrict__ HG,
    const h16* __restrict__ HZ, const h16* __restrict__ RT) {
    EH x;
    int s = i64s ? src[2 * e] : src[e];
    int t = i64d ? dst[2 * e] : dst[e];
    x.ok = 1.f;
    if (s < 0 || s >= N) { s = 0; x.ok = 0.f; }
    if (t < 0 || t >= N) { t = 0; x.ok = 0.f; }
    x.s = s;
    x.r0 = r_ij[e * 3 + 0];
    x.r1 = r_ij[e * 3 + 1];
    x.r2 = r_ij[e * 3 + 2];
    x.gs = *(const h4*)&HG[(size_t)s * 512 + (lane << 2)];
    x.gd = *(const h4*)&HG[(size_t)t * 512 + 256 + (lane << 2)];
    x.zv = *(const h4*)&HZ[(size_t)t * 256 + (lane << 2)];
    const float d2 = x.r0 * x.r0 + x.r1 * x.r1 + x.r2 * x.r2;
    int bin = (int)(sqrtf(d2) * ((float)RT_BINS / 4.0f));
    if (bin > RT_BINS - 1) bin = RT_BINS - 1;
    x.rt = *(const h4*)&RT[(size_t)bin * 256 + (lane << 2)];
    return x;
}

__device__ __forceinline__ void consume_edge16(
    const EH& x, int lane, h16* __restrict__ ACC) {
    // gate = GS[s] + GD[t] + RT[bin(d)]  (fp16 packed adds, then widen)
    const h4 g4 = x.gs + x.gd + x.rt;
    const float g0 = (float)g4.x, g1 = (float)g4.y;
    const float g2 = (float)g4.z, g3 = (float)g4.w;
    const float za = (float)x.zv.x, zb = (float)x.zv.y, zc = (float)x.zv.z;
    const float z0v = (float)x.zv.w;

    const float v0 = x.r0 * 3.5f, v1 = x.r1 * 3.5f, v2 = x.r2 * 3.5f;
    const float inv = rsqrtf(1.0f + v0 * v0 + v1 * v1 + v2 * v2);
    const float h0 = v0 * inv, h1 = v1 * inv, h2 = v2 * inv;
    const float uu = h0 * za + h1 * zb + h2 * zc;

    const float smsg = (g0 * z0v + g1 * uu) * x.ok;
    const float vm0 = (g2 * za + g3 * h0 * z0v) * x.ok;
    const float vm1 = (g2 * zb + g3 * h1 * z0v) * x.ok;
    const float vm2 = (g2 * zc + g3 * h2 * z0v) * x.ok;

    h16* ap = &ACC[(size_t)x.s * 256 + (lane << 2)];
    pk_add(ap,     smsg, vm0);
    pk_add(ap + 2, vm1,  vm2);
}

__global__ __launch_bounds__(256, 8) void edge_rt_k(
    const int* __restrict__ src, const int* __restrict__ dst,
    const float* __restrict__ r_ij, const h16* __restrict__ HG,
    const h16* __restrict__ HZ, const h16* __restrict__ RT,
    h16* __restrict__ ACC, int N, int E) {
    __shared__ int sFl[2];
    if (threadIdx.x == 0) {
        const u32* ps = (const u32*)src;
        const u32* pd = (const u32*)dst;
        int s64 = 1, d64 = 1;
        for (int i = 1; i < 128; i += 2) {
            if (ps[i] != 0u) s64 = 0;
            if (pd[i] != 0u) d64 = 0;
        }
        sFl[0] = s64;
        sFl[1] = d64;
    }
    __syncthreads();

    const int wid = threadIdx.x >> 6, lane = threadIdx.x & 63;
    const int i64s = sFl[0], i64d = sFl[1];
    const int nw = gridDim.x * 4;

    for (int e = blockIdx.x * 4 + wid; e < E; e += 2 * nw) {
        const int e2 = e + nw;
        EH A = load_edge16(e, lane, i64s, i64d, N, src, dst, r_ij, HG, HZ, RT);
        if (e2 < E) {   // wave-uniform
            EH B = load_edge16(e2, lane, i64s, i64d, N, src, dst, r_ij, HG, HZ, RT);
            consume_edge16(A, lane, ACC);
            consume_edge16(B, lane, ACC);
        } else {
            consume_edge16(A, lane, ACC);
        }
    }
}

// ---------------------------------------------------------------- node epilogue v4
// (verified round 10) de-interleave fp16 ACC, apply Ws/Wv, write out fully.
__global__ __launch_bounds__(256, 3) void nodepost4_k(
    const h16* __restrict__ ACC, float* __restrict__ out,
    const float* __restrict__ Ws, const float* __restrict__ Wv, int N) {
    __shared__ __align__(16) float sW[8192];     // [0..4095]=Ws, [4096..]=Wv
    __shared__ float sR[64 * 65];                // 64 virtual rows, pad 65
    for (int i = threadIdx.x * 4; i < 8192; i += 1024) {
        *(float4*)&sW[i] = (i < 4096) ? *(const float4*)&Ws[i]
                                      : *(const float4*)&Wv[i - 4096];
    }
    const int c4 = (threadIdx.x & 15) << 2;      // col offset 0..60
    const int rq = threadIdx.x >> 4;             // 0..15 -> rows rq*4..+3
    const int lim = N * 256;
    const int ntiles = (N + 15) >> 4;

    for (int tile = blockIdx.x; tile < ntiles; tile += gridDim.x) {
        const int n0 = tile << 4;
        const int base = n0 * 256;
        __syncthreads();
        for (int i = threadIdx.x * 4; i < 4096; i += 1024) {
            const int nl = i >> 8;               // node local 0..15
            const int k = (i & 255) >> 2;        // column 0..63
            h4 v = { (h16)0.f, (h16)0.f, (h16)0.f, (h16)0.f };
            if (base + i < lim) v = *(const h4*)&ACC[base + i];
            sR[(nl) * 65 + k] = (float)v.x;
            sR[(16 + nl) * 65 + k] = (float)v.y;
            sR[(32 + nl) * 65 + k] = (float)v.z;
            sR[(48 + nl) * 65 + k] = (float)v.w;
        }
        __syncthreads();

        const int rb = rq << 2;
        const int part = rb >> 4;
        const float* wb = &sW[(part == 0 ? 0 : 4096) + c4];
        float4 a0 = {0,0,0,0}, a1 = {0,0,0,0}, a2 = {0,0,0,0}, a3 = {0,0,0,0};
        const float* rp0 = &sR[(rb + 0) * 65];
        const float* rp1 = &sR[(rb + 1) * 65];
        const float* rp2 = &sR[(rb + 2) * 65];
        const float* rp3 = &sR[(rb + 3) * 65];
        #pragma unroll 8
        for (int k = 0; k < 64; ++k) {
            const float4 w = *(const float4*)&wb[k * 64];
            const float e0 = rp0[k], e1 = rp1[k], e2 = rp2[k], e3 = rp3[k];
            a0.x += e0 * w.x; a0.y += e0 * w.y; a0.z += e0 * w.z; a0.w += e0 * w.w;
            a1.x += e1 * w.x; a1.y += e1 * w.y; a1.z += e1 * w.z; a1.w += e1 * w.w;
            a2.x += e2 * w.x; a2.y += e2 * w.y; a2.z += e2 * w.z; a2.w += e2 * w.w;
            a3.x += e3 * w.x; a3.y += e3 * w.y; a3.z += e3 * w.z; a3.w += e3 * w.w;
        }
        #pragma unroll
        for (int i = 0; i < 4; ++i) {
            const int n = n0 + ((rb + i) & 15);
            if (n >= N) continue;
            const float4 av = (i == 0) ? a0 : (i == 1) ? a1 : (i == 2) ? a2 : a3;
            if (part == 0)
                *(float4*)&out[(size_t)n * 64 + c4] = av;
            else
                *(float4*)&out[(size_t)N * 64 + (size_t)n * 192 + (part - 1) * 64 + c4] = av;
        }
    }
}

// ---------------------------------------------------------------- full fallback
__global__ __launch_bounds__(512, 1) void edge_k(
    const int* __restrict__ src, const int* __restrict__ dst,
    const float* __restrict__ r_ij, const float* __restrict__ z0g,
    const float* __restrict__ z1g, const float* __restrict__ emb,
    const float* __restrict__ Wenc, const float* __restrict__ benc,
    const float* __restrict__ Wsrc, const float* __restrict__ bsrc,
    const float* __restrict__ Wdst, const float* __restrict__ bdst,
    const float* __restrict__ Wgate, const float* __restrict__ bgate,
    const float* __restrict__ Ws, const float* __restrict__ Wv,
    float* __restrict__ out, int N, int E)
{
    __shared__ float sWsrc[4096];
    __shared__ float sWdst[4096];
    __shared__ float sWg[16384];
    __shared__ float sWs[4096];
    __shared__ float sWv[4096];
    __shared__ float sWe[512];
    __shared__ float sB[64];
    __shared__ float sBg[256];
    __shared__ int sFl[2];

    if (threadIdx.x == 0) {
        const u32* ps = (const u32*)src;
        const u32* pd = (const u32*)dst;
        int s64 = 1, d64 = 1;
        for (int i = 1; i < 128; i += 2) {
            if (ps[i] != 0u) s64 = 0;
            if (pd[i] != 0u) d64 = 0;
        }
        sFl[0] = s64;
        sFl[1] = d64;
    }
    for (int i = threadIdx.x; i < 4096; i += 512) {
        sWsrc[i] = Wsrc[i];
        sWdst[i] = Wdst[i];
        sWs[i] = Ws[i];
        sWv[i] = Wv[i];
    }
    for (int i = threadIdx.x; i < 16384; i += 512) sWg[i] = Wgate[i];
    for (int i = threadIdx.x; i < 512; i += 512) sWe[i] = Wenc[i];
    if (threadIdx.x < 64)
        sB[threadIdx.x] = benc[threadIdx.x] + bsrc[threadIdx.x] + bdst[threadIdx.x];
    if (threadIdx.x < 256) sBg[threadIdx.x] = bgate[threadIdx.x];
    __syncthreads();

    const int wid = threadIdx.x >> 6, lane = threadIdx.x & 63;
    const int i64s = sFl[0], i64d = sFl[1];

    for (int e = blockIdx.x * 8 + wid; e < E; e += gridDim.x * 8) {
        const int s = i64s ? src[2 * e] : src[e];
        const int t = i64d ? dst[2 * e] : dst[e];
        if (s < 0 || s >= N || t < 0 || t >= N) continue;

        const float es = emb[s * 64 + lane];
        const float et = emb[t * 64 + lane];
        float de = sB[lane];
        #pragma unroll 8
        for (int k = 0; k < 64; ++k) {
            de += __shfl(es, k, 64) * sWsrc[(k << 6) + lane];
            de += __shfl(et, k, 64) * sWdst[(k << 6) + lane];
        }
        const float r0 = r_ij[e * 3 + 0];
        const float r1 = r_ij[e * 3 + 1];
        const float r2 = r_ij[e * 3 + 2];
        const float d = sqrtf(r0 * r0 + r1 * r1 + r2 * r2);
        #pragma unroll
        for (int m = 0; m < 8; ++m) {
            const float mu = (2.0f / 7.0f) * (float)m;
            const float tt = (d - mu) * 4.0f;
            de += __expf(-tt * tt) * sWe[m * 64 + lane];
        }

        const float v0 = r0 * 3.5f, v1 = r1 * 3.5f, v2 = r2 * 3.5f;
        const float inv = rsqrtf(1.0f + v0 * v0 + v1 * v1 + v2 * v2);
        const float h0 = v0 * inv, h1 = v1 * inv, h2 = v2 * inv;

        const float z0v = z0g[t * 64 + lane];
        const float za = z1g[t * 192 + lane];
        const float zb = z1g[t * 192 + 64 + lane];
        const float zc = z1g[t * 192 + 128 + lane];
        const float uu = h0 * za + h1 * zb + h2 * zc;

        float g0 = sBg[lane], g1 = sBg[64 + lane], g2 = sBg[128 + lane], g3 = sBg[192 + lane];
        #pragma unroll 8
        for (int k = 0; k < 64; ++k) {
            const float dk = __shfl(de, k, 64);
            const float* w = &sWg[(k << 8) + lane];
            g0 += dk * w[0];
            g1 += dk * w[64];
            g2 += dk * w[128];
            g3 += dk * w[192];
        }

        const float smsg = g0 * z0v + g1 * uu;
        const float vm0 = g2 * za + g3 * h0 * z0v;
        const float vm1 = g2 * zb + g3 * h1 * z0v;
        const float vm2 = g2 * zc + g3 * h2 * z0v;

        float p0 = 0.f, q0 = 0.f, q1 = 0.f, q2 = 0.f;
        #pragma unroll 8
        for (int k = 0; k < 64; ++k) {
            const float sk = __shfl(smsg, k, 64);
            const float a = __shfl(vm0, k, 64);
            const float b = __shfl(vm1, k, 64);
            const float c = __shfl(vm2, k, 64);
            p0 += sk * sWs[(k << 6) + lane];
            const float wv = sWv[(k << 6) + lane];
            q0 += a * wv;
            q1 += b * wv;
            q2 += c * wv;
        }

        atomicAdd(&out[s * 64 + lane], p0);
        const int b1 = N * 64 + s * 192 + lane;
        atomicAdd(&out[b1], q0);
        atomicAdd(&out[b1 + 64], q1);
        atomicAdd(&out[b1 + 128], q2);
    }
}

extern "C" void kernel_launch(void* const* d_in, const int* in_sizes, int n_in,
                              void* d_out, int out_size, void* d_ws, size_t ws_size,
                              hipStream_t stream) {
    const int* src = (const int*)d_in[0];
    const int* dst = (const int*)d_in[1];
    const float* r_ij = (const float*)d_in[2];
    const float* z0g  = (const float*)d_in[3];
    const float* z1g  = (const float*)d_in[4];
    const float* emb  = (const float*)d_in[5];
    const float* Wenc = (const float*)d_in[6];
    const float* benc = (const float*)d_in[7];
    const float* Wsrc = (const float*)d_in[8];
    const float* bsrc = (const float*)d_in[9];
    const float* Wdst = (const float*)d_in[10];
    const float* bdst = (const float*)d_in[11];
    const float* Wgate = (const float*)d_in[12];
    const float* bgate = (const float*)d_in[13];
    const float* Ws = (const float*)d_in[14];
    const float* Wv = (const float*)d_in[15];

    const int N = out_size / 256;                    // out0 N*64 + out1 N*192
    int E = in_sizes[0];
    if (in_sizes[2] / 3 < E) E = in_sizes[2] / 3;    // robustness

    float* ws = (float*)d_ws;
    // HG: N*256 float-slots | HZ: N*128 | ACC: N*128 | RT: 4096*256 h16 = 512K slots
    const size_t need = ((size_t)WS_GS + (size_t)N * 512u
                         + (size_t)RT_BINS * 128u + 16u) * sizeof(float);

    if (ws != nullptr && ws_size >= need) {
        compose_k<<<73, 256, 0, stream>>>(Wsrc, Wdst, Wenc, benc, bsrc, bdst,
                                          Wgate, bgate, ws);
        h16* HG = (h16*)(ws + WS_GS);
        h16* HZ = HG + (size_t)N * 512;
        h16* ACC = HZ + (size_t)N * 256;
        h16* RT = ACC + (size_t)N * 256;
        radtab_k<<<RT_BINS, 256, 0, stream>>>(ws + WS_WEG, ws + WS_BALL, RT);
        nodepre3_k<<<256, 512, 0, stream>>>(emb, ws + WS_WSG, HG, N);
        hz_k<<<1024, 256, 0, stream>>>(z0g, z1g, HZ, ACC, N);
        edge_rt_k<<<2048, 256, 0, stream>>>(src, dst, r_ij, HG, HZ, RT, ACC, N, E);
        nodepost4_k<<<2048, 256, 0, stream>>>(ACC, (float*)d_out, Ws, Wv, N);
    } else {
        zero_k<<<2048, 256, 0, stream>>>((float*)d_out, out_size);
        edge_k<<<2048, 512, 0, stream>>>(src, dst, r_ij, z0g, z1g, emb, Wenc, benc,
                                         Wsrc, bsrc, Wdst, bdst, Wgate, bgate, Ws, Wv,
                                         (float*)d_out, N, E);
    }
}